// Round 4
// baseline (705.924 us; speedup 1.0000x reference)
//
#include <hip/hip_runtime.h>
#include <stdint.h>
#include <math.h>

// Match numpy's non-fused multiply-add rounding in distance/plane tests:
// a wrong argmin (or a boundary-mask flip) cascades into an O(1) output error.
// R1-R3 passed with absmax 0.0 using exactly these expression forms — keep them.
#pragma clang fp contract(off)

#define BLOCK 1024
#define NW (BLOCK / 64)
#define PT 8                    // points per thread per Phase-A step
#define PB 4                    // entries per thread per Phase-B step
#define MAX_ITERS 50
#define EPS_NORM 1e-8f
#define EPS_SEP (-1e-6f)

// One block per target.
// Phase A: full-N scans, 8 points/thread/step (25 steps for N=200k). Mask is
//          one LDS byte per thread per step (bit i = point survives): read as
//          broadcast dword + bfe, written via shfl_xor byte-merge + one b32
//          store per 4 lanes. No ballot/atomic on lean scans; when the
//          incoming count fits 2*CAP the scan also compacts survivors into an
//          LDS list (shfl prefix-scan + 1 atomic/wave/step).
// Phase B: scan only the compacted list, 4 entries/thread, re-compacting in
//          place (append positions provably stay below any unread segment).
// Early-out: empty set => all remaining (a,b) identical; bulk-write and exit.
__global__ __launch_bounds__(BLOCK, 1) void convex_plane_kernel(
    const float* __restrict__ pc, const float* __restrict__ tg,
    float* __restrict__ out, int N, int M, int CAP, int stepsA)
{
    extern __shared__ uint32_t smem[];
    const int tid  = threadIdx.x;
    const int lane = tid & 63;
    const int wv   = tid >> 6;
    const int m    = blockIdx.x;

    const int maskW = stepsA * (BLOCK / 4);     // mask words (1 byte/thread/step)
    uint32_t* mask  = smem;                     // [maskW]
    int*      list  = (int*)(smem + maskW);     // [CAP]
    float*    red_d = (float*)(list + CAP);     // [NW]
    int*      red_i = (int*)(red_d + NW);       // [NW]
    int*      cw    = red_i + NW;               // [NW]
    int*      bcast = cw + NW;                  // [2] {argmin idx, total count}
    int*      cnt   = bcast + 2;                // [1] list-append cursor

    const float tx = tg[3*m+0], ty = tg[3*m+1], tz = tg[3*m+2];
    const float t2 = tx*tx + ty*ty + tz*tz;

    float* out_a = out;
    float* out_b = out + (size_t)MAX_ITERS * (size_t)M * 3;

    // cross-wave finish: lexicographic (d2,idx) argmin + per-thread count sum;
    // {idx,count} returned to ALL threads via barrier-protected bcast.
    auto finish = [&](float dmin, int imin, int mycnt) -> int2 {
        #pragma unroll
        for (int off = 32; off > 0; off >>= 1) {
            float od = __shfl_down(dmin, off, 64);
            int   oi = __shfl_down(imin, off, 64);
            int   oc = __shfl_down(mycnt, off, 64);
            if (od < dmin || (od == dmin && oi < imin)) { dmin = od; imin = oi; }
            mycnt += oc;
        }
        if (lane == 0) { red_d[wv] = dmin; red_i[wv] = imin; cw[wv] = mycnt; }
        __syncthreads();
        if (wv == 0) {
            float bd = (lane < NW) ? red_d[lane] : INFINITY;
            int   bi = (lane < NW) ? red_i[lane] : 0;
            int   c  = (lane < NW) ? cw[lane]    : 0;
            #pragma unroll
            for (int off = 8; off > 0; off >>= 1) {
                float od = __shfl_down(bd, off, 64);
                int   oi = __shfl_down(bi, off, 64);
                int   oc = __shfl_down(c,  off, 64);
                if (od < bd || (od == bd && oi < bi)) { bd = od; bi = oi; }
                c += oc;
            }
            if (lane == 0) { bcast[0] = bi; bcast[1] = c; }
        }
        __syncthreads();
        int2 r; r.x = bcast[0]; r.y = bcast[1];
        return r;
    };

    // Phase A: full-N scan, PT points per thread.
    auto scanA = [&](bool first, bool build,
                     float ax, float ay, float az, float b) -> int2 {
        if (build && tid == 0) cnt[0] = 0;
        __syncthreads();
        float dmin = INFINITY;
        int   imin = 0;
        int   mycnt = 0;
        for (int s = 0; s < stepsA; ++s) {
            const int i0   = (s * BLOCK + tid) * PT;       // 8 consecutive points
            const int wofs = s * (BLOCK / 4) + (tid >> 2); // this group's word
            uint32_t oldb;
            if (first) oldb = 0xFFu;
            else {
                uint32_t w = mask[wofs];                   // 4-lane broadcast read
                oldb = (w >> (8 * (tid & 3))) & 0xFFu;
            }
            float px[PT], py[PT], pz[PT];
            #pragma unroll
            for (int j = 0; j < PT; ++j) {                 // issue all loads first
                const int i = i0 + j;
                if (((oldb >> j) & 1u) && i < N) {
                    const float* p = pc + 3 * (size_t)i;
                    px[j] = p[0]; py[j] = p[1]; pz[j] = p[2];
                }
            }
            uint32_t newb = 0;
            #pragma unroll
            for (int j = 0; j < PT; ++j) {
                const int i = i0 + j;
                if (((oldb >> j) & 1u) && i < N) {
                    bool keep;
                    if (first) keep = true;
                    else {
                        float dt = ax*px[j] + ay*py[j] + az*pz[j] - b;
                        keep = (dt < EPS_SEP);             // !(dt >= EPS_SEP)
                    }
                    if (keep) {
                        newb |= (1u << j);
                        float p2 = px[j]*px[j] + py[j]*py[j] + pz[j]*pz[j];
                        float tp = tx*px[j] + ty*py[j] + tz*pz[j];
                        float d2 = t2 + p2 - 2.0f*tp;      // reference's exact form
                        if (d2 < dmin) { dmin = d2; imin = i; } // ascending i
                    }
                }
            }
            // merge 4 bytes -> word; one store per 4 lanes
            uint32_t v = newb << (8 * (tid & 3));
            v |= __shfl_xor(v, 1, 64);
            v |= __shfl_xor(v, 2, 64);
            if ((tid & 3) == 0) mask[wofs] = v;
            mycnt += (int)__popc(newb);

            if (build) {                                   // compact survivors
                int c = (int)__popc(newb);
                int incl = c;
                #pragma unroll
                for (int off = 1; off < 64; off <<= 1) {
                    int o = __shfl_up(incl, off, 64);
                    if (lane >= off) incl += o;
                }
                const int excl = incl - c;
                const int tot  = __shfl(incl, 63, 64);
                int wbase = 0;
                if (lane == 0) wbase = atomicAdd(cnt, tot);
                wbase = __shfl(wbase, 0, 64);
                int pos = wbase + excl;
                #pragma unroll
                for (int j = 0; j < PT; ++j) {
                    if ((newb >> j) & 1u) {
                        if (pos < CAP) list[pos] = i0 + j;
                        ++pos;
                    }
                }
            }
        }
        return finish(dmin, imin, mycnt);
    };

    // Phase B: list scan, PB entries per thread, in-place re-compaction.
    // Safe: reads of segment s complete (barrier) before appends, and append
    // positions (< cumulative survivors <= cumulative reads) never reach the
    // start of any unread segment.
    auto scanB = [&](int count, float ax, float ay, float az, float b) -> int2 {
        if (tid == 0) cnt[0] = 0;
        __syncthreads();
        float dmin = INFINITY;
        int   imin = 0;
        const int per = BLOCK * PB;
        const int bsteps = (count + per - 1) / per;
        for (int s = 0; s < bsteps; ++s) {
            const int e0 = s * per + tid * PB;
            int jv[PB]; float d2v[PB];
            uint32_t keepm = 0;
            #pragma unroll
            for (int q = 0; q < PB; ++q) {
                const int e = e0 + q;
                if (e < count) {
                    const int j = list[e];
                    jv[q] = j;
                    const float* p = pc + 3 * (size_t)j;
                    float px = p[0], py = p[1], pz = p[2];
                    float dt = ax*px + ay*py + az*pz - b;
                    if (dt < EPS_SEP) {
                        keepm |= (1u << q);
                        float p2 = px*px + py*py + pz*pz;
                        float tp = tx*px + ty*py + tz*pz;
                        d2v[q] = t2 + p2 - 2.0f*tp;
                    }
                }
            }
            __syncthreads();                       // reads done before appends
            int c = (int)__popc(keepm);
            int incl = c;
            #pragma unroll
            for (int off = 1; off < 64; off <<= 1) {
                int o = __shfl_up(incl, off, 64);
                if (lane >= off) incl += o;
            }
            const int excl = incl - c;
            const int tot  = __shfl(incl, 63, 64);
            int wbase = 0;
            if (lane == 0) wbase = atomicAdd(cnt, tot);
            wbase = __shfl(wbase, 0, 64);
            int pos = wbase + excl;
            #pragma unroll
            for (int q = 0; q < PB; ++q) {
                if ((keepm >> q) & 1u) {
                    list[pos] = jv[q];
                    // list order arbitrary -> lexicographic for exact ties
                    if (d2v[q] < dmin || (d2v[q] == dmin && jv[q] < imin)) {
                        dmin = d2v[q]; imin = jv[q];
                    }
                    ++pos;
                }
            }
        }
        __syncthreads();                           // all appends/atomics done
        float dd = dmin; int ii = imin;
        #pragma unroll
        for (int off = 32; off > 0; off >>= 1) {
            float od = __shfl_down(dd, off, 64);
            int   oi = __shfl_down(ii, off, 64);
            if (od < dd || (od == dd && oi < ii)) { dd = od; ii = oi; }
        }
        if (lane == 0) { red_d[wv] = dd; red_i[wv] = ii; }
        __syncthreads();
        if (wv == 0) {
            float bd = (lane < NW) ? red_d[lane] : INFINITY;
            int   bi = (lane < NW) ? red_i[lane] : 0;
            #pragma unroll
            for (int off = 8; off > 0; off >>= 1) {
                float od = __shfl_down(bd, off, 64);
                int   oi = __shfl_down(bi, off, 64);
                if (od < bd || (od == bd && oi < bi)) { bd = od; bi = oi; }
            }
            if (lane == 0) { bcast[0] = bi; bcast[1] = cnt[0]; }
        }
        __syncthreads();
        int2 r; r.x = bcast[0]; r.y = bcast[1];
        return r;
    };

    bool comp = false;
    int2 rc = scanA(true, false, 0.f, 0.f, 0.f, 0.f);
    int idx = rc.x, count = rc.y;                  // count = N here

    for (int k = 0; k < MAX_ITERS; ++k) {
        const float cx = pc[3*idx+0], cy = pc[3*idx+1], cz = pc[3*idx+2];
        const float vx = cx - tx, vy = cy - ty, vz = cz - tz;
        const float nrm = sqrtf(vx*vx + vy*vy + vz*vz);
        const float den = nrm + EPS_NORM;
        const float ax = vx / den, ay = vy / den, az = vz / den;
        const float b  = ax*cx + ay*cy + az*cz;    // b = sum(a * closest)

        if (count == 0) {
            // Set was empty when idx was computed (idx==0): every remaining
            // iteration emits these exact values. Bulk-write and retire.
            for (int q = tid; q < MAX_ITERS - k; q += BLOCK) {
                const int kk = k + q;
                const size_t oa = ((size_t)kk * M + m) * 3;
                out_a[oa+0] = ax; out_a[oa+1] = ay; out_a[oa+2] = az;
                out_b[(size_t)kk * M + m] = b;
            }
            return;
        }
        if (tid == 0) {
            const size_t oa = ((size_t)k * M + m) * 3;
            out_a[oa+0] = ax; out_a[oa+1] = ay; out_a[oa+2] = az;
            out_b[(size_t)k * M + m] = b;
        }
        if (k + 1 < MAX_ITERS) {                   // last update unobservable
            if (comp) {
                rc = scanB(count, ax, ay, az, b);
            } else {
                const bool build = (count <= 2 * CAP);  // opportunistic compact
                rc = scanA(false, build, ax, ay, az, b);
                if (build && rc.y <= CAP) comp = true;
            }
            idx = rc.x; count = rc.y;
        }
    }
}

extern "C" void kernel_launch(void* const* d_in, const int* in_sizes, int n_in,
                              void* d_out, int out_size, void* d_ws, size_t ws_size,
                              hipStream_t stream) {
    const float* pc = (const float*)d_in[0];
    const float* tg = (const float*)d_in[1];
    float* out = (float*)d_out;
    const int N = in_sizes[0] / 3;
    const int M = in_sizes[1] / 3;
    const int stepsA = (N + BLOCK * PT - 1) / (BLOCK * PT);
    const size_t maskB  = (size_t)stepsA * (BLOCK / 4) * sizeof(uint32_t);
    const size_t fixedB = NW * (2 * sizeof(int) + sizeof(float)) + 3 * sizeof(int);

    int CAP = 32768;                               // 128 KB list; total ~157 KB LDS
    size_t smem = maskB + (size_t)CAP * sizeof(int) + fixedB;
    if (hipFuncSetAttribute((const void*)convex_plane_kernel,
                            hipFuncAttributeMaxDynamicSharedMemorySize,
                            (int)smem) != hipSuccess) {
        CAP = 8192;                                // stay within default 64 KB
        smem = maskB + (size_t)CAP * sizeof(int) + fixedB;
    }
    convex_plane_kernel<<<M, BLOCK, smem, stream>>>(pc, tg, out, N, M, CAP, stepsA);
}